// Round 12
// baseline (148.772 us; speedup 1.0000x reference)
//
#include <hip/hip_runtime.h>

// Log-sparse attention, B=4 H=8 L=4096 E=64 fp32, win_len<=32.
// Quad-per-query. Round-12: NO LDS AT ALL. R11 showed we're latency-bound
// (occ 20%, VALU 31%) and the bf16 LDS pipeline's pack/unpack is ~40% of
// VALU work while the window working set (49KB/block, shared with XCD
// neighbors) is L2-resident anyway. All K/V reads now direct global fp32:
// no staging, no barrier, no unpack, LDS=0 (occupancy = f(VGPR) only),
// and full-fp32 accuracy. Scores distributed across quad; DPP softmax.

constexpr int L    = 4096;
constexpr int E    = 64;
constexpr int QPB  = 64;             // queries per block (256 thr / 4)
constexpr int WMAX = 32;
constexpr int TPB  = L / QPB;        // 64 tiles per (b,h)
constexpr int NP2  = 6;              // pow2 dists 64..2048

// ---- DPP quad_perm cross-lane (VALU pipe; 4-lane groups) ----
template<int CTRL>
__device__ __forceinline__ float dppf(float x) {
    return __int_as_float(__builtin_amdgcn_update_dpp(
        0, __float_as_int(x), CTRL, 0xF, 0xF, true));
}
__device__ __forceinline__ float quad_sum(float x) {
    x += dppf<0xB1>(x);   // quad_perm [1,0,3,2]
    x += dppf<0x4E>(x);   // quad_perm [2,3,0,1]
    return x;
}
__device__ __forceinline__ float quad_max(float x) {
    x = fmaxf(x, dppf<0xB1>(x));
    x = fmaxf(x, dppf<0x4E>(x));
    return x;
}
__device__ __forceinline__ float quad_bcast(float x, int r) {
    switch (r & 3) {
    case 0:  return dppf<0x00>(x);
    case 1:  return dppf<0x55>(x);
    case 2:  return dppf<0xAA>(x);
    default: return dppf<0xFF>(x);
    }
}

__global__ __launch_bounds__(256) void logsparse_attn(
    const float* __restrict__ q,
    const float* __restrict__ k,
    const float* __restrict__ v,
    float* __restrict__ out,
    const int* __restrict__ win_ptr)
{
    const int bid = blockIdx.x, nb = gridDim.x;
    int swz = bid;
    if ((nb & 7) == 0) {                       // bijective XCD swizzle
        const int cpx = nb >> 3;
        swz = (bid & 7) * cpx + (bid >> 3);
    }
    const int bh  = swz / TPB;
    const int t   = (swz % TPB) * QPB;
    const int tid = threadIdx.x;
    const int qid = tid >> 2;                  // query within block (0..63)
    const int s   = tid & 3;                   // lane within quad
    const int i   = t + qid;                   // this quad's query position
    const int ce  = s * 16;                    // chunk base element
    int win = *win_ptr; win = min(win, WMAX);

    const size_t base = (size_t)bh * (L * E);
    const float* kb = k + base;
    const float* vb = v + base;

    // ---- this lane's q chunk (16 fp32), scale folded (1/8) ----
    float qv[16];
    {
        const float* qp = q + base + (size_t)i * E + ce;
        #pragma unroll
        for (int u = 0; u < 4; ++u) {
            float4 f = *(const float4*)(qp + u * 4);
            qv[u*4+0] = f.x * 0.125f; qv[u*4+1] = f.y * 0.125f;
            qv[u*4+2] = f.z * 0.125f; qv[u*4+3] = f.w * 0.125f;
        }
    }

    // ---- scores, distributed: lane s owns keys a with a%4==s ----
    float ws[9];                               // window keys o = 4k+s
    float wp[2];                               // pow2 keys
    #pragma unroll
    for (int kk = 0; kk < 9; ++kk) ws[kk] = -1e30f;
    wp[0] = wp[1] = -1e30f;

    // window offsets 0..32, K row direct from global (fp32, 64B/lane)
    #pragma unroll
    for (int o = 0; o <= WMAX; ++o) {
        const float* kr = kb + (size_t)max(i - o, 0) * E + ce;
        float a0 = 0.f, a1 = 0.f, a2 = 0.f, a3 = 0.f;
        #pragma unroll
        for (int u = 0; u < 4; ++u) {
            float4 f = *(const float4*)(kr + u * 4);
            a0 = fmaf(f.x, qv[u*4+0], a0); a1 = fmaf(f.y, qv[u*4+1], a1);
            a2 = fmaf(f.z, qv[u*4+2], a2); a3 = fmaf(f.w, qv[u*4+3], a3);
        }
        float sv = quad_sum((a0 + a1) + (a2 + a3));
        const bool isp2  = (o > 0) && ((o & (o - 1)) == 0);
        const bool valid = ((o <= win) || isp2) && (o <= i);
        sv = valid ? sv : -1e30f;
        if (s == (o & 3)) ws[o >> 2] = sv;
        if ((o & 1) == 1) __builtin_amdgcn_sched_barrier(0);  // <=2 rows in flight
    }

    // pow2 dists 64..2048
    #pragma unroll
    for (int dd = 0; dd < NP2; ++dd) {
        const int d = 64 << dd;
        if (t + QPB - 1 >= d) {                // block-uniform skip
            const float* kr = kb + (size_t)max(i - d, 0) * E + ce;
            float a0 = 0.f, a1 = 0.f, a2 = 0.f, a3 = 0.f;
            #pragma unroll
            for (int u = 0; u < 4; ++u) {
                float4 f = *(const float4*)(kr + u * 4);
                a0 = fmaf(f.x, qv[u*4+0], a0); a1 = fmaf(f.y, qv[u*4+1], a1);
                a2 = fmaf(f.z, qv[u*4+2], a2); a3 = fmaf(f.w, qv[u*4+3], a3);
            }
            float sv = quad_sum((a0 + a1) + (a2 + a3));
            sv = (i >= d) ? sv : -1e30f;
            if (s == ((WMAX + 1 + dd) & 3)) wp[dd < 4 ? 0 : 1] = sv;
        }
        if (dd & 1) __builtin_amdgcn_sched_barrier(0);
    }

    // ---- softmax across the quad's distributed scores ----
    float ml = ws[0];
    #pragma unroll
    for (int kk = 1; kk < 9; ++kk) ml = fmaxf(ml, ws[kk]);
    ml = fmaxf(ml, fmaxf(wp[0], wp[1]));
    const float m = quad_max(ml);

    float ew[9], ep0, ep1, dl = 0.f;
    #pragma unroll
    for (int kk = 0; kk < 9; ++kk) { ew[kk] = __expf(ws[kk] - m); dl += ew[kk]; }
    ep0 = __expf(wp[0] - m); ep1 = __expf(wp[1] - m); dl += ep0 + ep1;
    const float inv = 1.0f / quad_sum(dl);
    #pragma unroll
    for (int kk = 0; kk < 9; ++kk) ew[kk] *= inv;
    ep0 *= inv; ep1 *= inv;

    // ---- PV: V rows direct from global (fp32); acc[16]/lane ----
    float acc[16];
    #pragma unroll
    for (int e = 0; e < 16; ++e) acc[e] = 0.f;

    #pragma unroll
    for (int o = 0; o <= WMAX; ++o) {
        const float pd = quad_bcast(ew[o >> 2], o & 3);   // 0 if masked
        const float* vr = vb + (size_t)max(i - o, 0) * E + ce;
        #pragma unroll
        for (int u = 0; u < 4; ++u) {
            float4 f = *(const float4*)(vr + u * 4);
            acc[u*4+0] = fmaf(f.x, pd, acc[u*4+0]);
            acc[u*4+1] = fmaf(f.y, pd, acc[u*4+1]);
            acc[u*4+2] = fmaf(f.z, pd, acc[u*4+2]);
            acc[u*4+3] = fmaf(f.w, pd, acc[u*4+3]);
        }
        if ((o & 1) == 1) __builtin_amdgcn_sched_barrier(0);
    }

    #pragma unroll
    for (int dd = 0; dd < NP2; ++dd) {
        const int d = 64 << dd;
        if (t + QPB - 1 >= d) {                // block-uniform skip
            const float pd = quad_bcast(dd < 4 ? ep0 : ep1, (WMAX + 1 + dd) & 3);
            const float* vr = vb + (size_t)max(i - d, 0) * E + ce;
            #pragma unroll
            for (int u = 0; u < 4; ++u) {
                float4 f = *(const float4*)(vr + u * 4);
                acc[u*4+0] = fmaf(f.x, pd, acc[u*4+0]);
                acc[u*4+1] = fmaf(f.y, pd, acc[u*4+1]);
                acc[u*4+2] = fmaf(f.z, pd, acc[u*4+2]);
                acc[u*4+3] = fmaf(f.w, pd, acc[u*4+3]);
            }
        }
        if (dd & 1) __builtin_amdgcn_sched_barrier(0);
    }

    // ---- write this lane's 64B chunk (quad writes contiguous 256B) ----
    float* op = out + base + (size_t)i * E + ce;
    #pragma unroll
    for (int u = 0; u < 4; ++u) {
        float4 o4;
        o4.x = acc[u*4+0]; o4.y = acc[u*4+1];
        o4.z = acc[u*4+2]; o4.w = acc[u*4+3];
        *(float4*)(op + u * 4) = o4;
    }
}

extern "C" void kernel_launch(void* const* d_in, const int* in_sizes, int n_in,
                              void* d_out, int out_size, void* d_ws, size_t ws_size,
                              hipStream_t stream) {
    const float* q = (const float*)d_in[0];
    const float* k = (const float*)d_in[1];
    const float* v = (const float*)d_in[2];
    const int* win = (const int*)d_in[3];
    float* out = (float*)d_out;

    const int n_rows = in_sizes[0] / E;        // B*H*L = 131072
    const int blocks = n_rows / QPB;           // 2048
    logsparse_attn<<<blocks, 256, 0, stream>>>(q, k, v, out, win);
}

// Round 13
// 64.762 us; speedup vs baseline: 2.2972x; 2.2972x over previous
//
#include <hip/hip_runtime.h>

// Log-sparse attention, B=4 H=8 L=4096 E=64 fp32, win_len<=32.
// Quad-per-query. Round-13: R11 structure EXACTLY (conflict-free 160/40B
// LDS bf16 K+V staged upfront, one barrier, plain launch_bounds(256))
// MINUS all compute-loop sched_barrier(0)s. R12 proved the barriers cap
// memory-level parallelism (2 rows in flight -> VALUBusy 13.7%); the quad
// structure's ~50-float live set no longer needs them as spill protection.
// Let the scheduler software-pipeline the unrolled score/PV loops.

constexpr int L     = 4096;
constexpr int E     = 64;
constexpr int QPB   = 64;            // queries per block (256 thr / 4)
constexpr int WMAX  = 32;
constexpr int WROWS = QPB + WMAX;    // 96 staged rows
constexpr int RS    = 160;           // LDS row stride bytes
constexpr int CS    = 40;            // chunk stride bytes (32 data + 8 pad)
constexpr int VOFF  = WROWS * RS;    // V region offset (15360)
constexpr int TPB   = L / QPB;       // 64 tiles per (b,h)
constexpr int NP2   = 6;             // pow2 dists 64..2048

__device__ __forceinline__ unsigned pack2_bf16(float a, float b) {
    unsigned ua = __float_as_uint(a);
    unsigned ub = __float_as_uint(b);
    unsigned ra = (ua + 0x7FFFu + ((ua >> 16) & 1u)) >> 16;  // RNE
    unsigned rb = (ub + 0x7FFFu + ((ub >> 16) & 1u)) >> 16;
    return ra | (rb << 16);
}
__device__ __forceinline__ float bf_lo(unsigned w) { return __uint_as_float(w << 16); }
__device__ __forceinline__ float bf_hi(unsigned w) { return __uint_as_float(w & 0xFFFF0000u); }

// ---- DPP quad_perm cross-lane (VALU pipe; 4-lane groups) ----
template<int CTRL>
__device__ __forceinline__ float dppf(float x) {
    return __int_as_float(__builtin_amdgcn_update_dpp(
        0, __float_as_int(x), CTRL, 0xF, 0xF, true));
}
__device__ __forceinline__ float quad_sum(float x) {
    x += dppf<0xB1>(x);   // quad_perm [1,0,3,2]
    x += dppf<0x4E>(x);   // quad_perm [2,3,0,1]
    return x;
}
__device__ __forceinline__ float quad_max(float x) {
    x = fmaxf(x, dppf<0xB1>(x));
    x = fmaxf(x, dppf<0x4E>(x));
    return x;
}
__device__ __forceinline__ float quad_bcast(float x, int r) {
    switch (r & 3) {
    case 0:  return dppf<0x00>(x);
    case 1:  return dppf<0x55>(x);
    case 2:  return dppf<0xAA>(x);
    default: return dppf<0xFF>(x);
    }
}

__global__ __launch_bounds__(256) void logsparse_attn(
    const float* __restrict__ q,
    const float* __restrict__ k,
    const float* __restrict__ v,
    float* __restrict__ out,
    const int* __restrict__ win_ptr)
{
    __shared__ alignas(16) unsigned char buf[2 * WROWS * RS];   // 30720 B

    const int bid = blockIdx.x, nb = gridDim.x;
    int swz = bid;
    if ((nb & 7) == 0) {                       // bijective XCD swizzle
        const int cpx = nb >> 3;
        swz = (bid & 7) * cpx + (bid >> 3);
    }
    const int bh  = swz / TPB;
    const int t   = (swz % TPB) * QPB;
    const int tid = threadIdx.x;
    const int qid = tid >> 2;                  // query within block (0..63)
    const int s   = tid & 3;                   // lane within quad = chunk id
    const int i   = t + qid;                   // this quad's query position
    const int ce  = s * 16;                    // chunk base element
    int win = *win_ptr; win = min(win, WMAX);

    const size_t base = (size_t)bh * (L * E);
    const float* kb = k + base;
    const float* vb = v + base;

    // ---- this lane's q chunk (16 fp32), scale folded (1/8) ----
    float qv[16];
    {
        const float* qp = q + base + (size_t)i * E + ce;
        #pragma unroll
        for (int u = 0; u < 4; ++u) {
            float4 f = *(const float4*)(qp + u * 4);
            qv[u*4+0] = f.x * 0.125f; qv[u*4+1] = f.y * 0.125f;
            qv[u*4+2] = f.z * 0.125f; qv[u*4+3] = f.w * 0.125f;
        }
    }

    // ---- stage K AND V window rows [t-32, t+64) as bf16, chunked layout ----
    // piece w (4 elems) of row r -> region + r*160 + (w>>2)*40 + (w&3)*8
    #pragma unroll
    for (int it = 0; it < 6; ++it) {
        int idx = tid + it * 256;
        int r = idx >> 4, w = idx & 15;
        int cc = w >> 2, p = w & 3;
        int j = max(t - WMAX + r, 0);
        float4 fk = *(const float4*)(kb + (size_t)j * E + w * 4);
        float4 fv = *(const float4*)(vb + (size_t)j * E + w * 4);
        uint2 pk; pk.x = pack2_bf16(fk.x, fk.y); pk.y = pack2_bf16(fk.z, fk.w);
        uint2 pv; pv.x = pack2_bf16(fv.x, fv.y); pv.y = pack2_bf16(fv.z, fv.w);
        *(uint2*)(buf + r * RS + cc * CS + p * 8) = pk;
        *(uint2*)(buf + VOFF + r * RS + cc * CS + p * 8) = pv;
    }
    __syncthreads();                 // the ONLY barrier in the kernel

    // ---- scores, distributed: lane s owns keys a with a%4==s ----
    float ws[9];
    float wp[2];
    #pragma unroll
    for (int kk = 0; kk < 9; ++kk) ws[kk] = -60000.f;
    wp[0] = wp[1] = -60000.f;

    // window offsets 0..32 from LDS K (4x b64 per lane, conflict-free)
    #pragma unroll
    for (int o = 0; o <= WMAX; ++o) {
        const unsigned char* rp = buf + (qid + WMAX - o) * RS + s * CS;
        uint2 u0 = *(const uint2*)(rp);
        uint2 u1 = *(const uint2*)(rp + 8);
        uint2 u2 = *(const uint2*)(rp + 16);
        uint2 u3 = *(const uint2*)(rp + 24);
        float a0 = 0.f, a1 = 0.f, a2 = 0.f, a3 = 0.f;
        a0 = fmaf(bf_lo(u0.x), qv[0],  a0); a1 = fmaf(bf_hi(u0.x), qv[1],  a1);
        a2 = fmaf(bf_lo(u0.y), qv[2],  a2); a3 = fmaf(bf_hi(u0.y), qv[3],  a3);
        a0 = fmaf(bf_lo(u1.x), qv[4],  a0); a1 = fmaf(bf_hi(u1.x), qv[5],  a1);
        a2 = fmaf(bf_lo(u1.y), qv[6],  a2); a3 = fmaf(bf_hi(u1.y), qv[7],  a3);
        a0 = fmaf(bf_lo(u2.x), qv[8],  a0); a1 = fmaf(bf_hi(u2.x), qv[9],  a1);
        a2 = fmaf(bf_lo(u2.y), qv[10], a2); a3 = fmaf(bf_hi(u2.y), qv[11], a3);
        a0 = fmaf(bf_lo(u3.x), qv[12], a0); a1 = fmaf(bf_hi(u3.x), qv[13], a1);
        a2 = fmaf(bf_lo(u3.y), qv[14], a2); a3 = fmaf(bf_hi(u3.y), qv[15], a3);
        float sv = quad_sum((a0 + a1) + (a2 + a3));
        const bool isp2  = (o > 0) && ((o & (o - 1)) == 0);
        const bool valid = ((o <= win) || isp2) && (o <= i);
        sv = valid ? sv : -60000.f;
        if (s == (o & 3)) ws[o >> 2] = sv;
    }

    // pow2 dists 64..2048 (global fp32; quad reads one contiguous 256B row)
    #pragma unroll
    for (int dd = 0; dd < NP2; ++dd) {
        const int d = 64 << dd;
        if (t + QPB - 1 >= d) {                // block-uniform skip
            const int j = max(i - d, 0);
            const float* kr = kb + (size_t)j * E + ce;
            float a0 = 0.f, a1 = 0.f, a2 = 0.f, a3 = 0.f;
            #pragma unroll
            for (int u = 0; u < 4; ++u) {
                float4 f = *(const float4*)(kr + u * 4);
                a0 = fmaf(f.x, qv[u*4+0], a0); a1 = fmaf(f.y, qv[u*4+1], a1);
                a2 = fmaf(f.z, qv[u*4+2], a2); a3 = fmaf(f.w, qv[u*4+3], a3);
            }
            float sv = quad_sum((a0 + a1) + (a2 + a3));
            sv = (i >= d) ? sv : -60000.f;
            if (s == ((WMAX + 1 + dd) & 3)) wp[dd < 4 ? 0 : 1] = sv;
        }
    }

    // ---- softmax across the quad's distributed scores ----
    float ml = ws[0];
    #pragma unroll
    for (int kk = 1; kk < 9; ++kk) ml = fmaxf(ml, ws[kk]);
    ml = fmaxf(ml, fmaxf(wp[0], wp[1]));
    const float m = quad_max(ml);

    float ew[9], ep0, ep1, dl = 0.f;
    #pragma unroll
    for (int kk = 0; kk < 9; ++kk) { ew[kk] = __expf(ws[kk] - m); dl += ew[kk]; }
    ep0 = __expf(wp[0] - m); ep1 = __expf(wp[1] - m); dl += ep0 + ep1;
    const float inv = 1.0f / quad_sum(dl);
    #pragma unroll
    for (int kk = 0; kk < 9; ++kk) ew[kk] *= inv;
    ep0 *= inv; ep1 *= inv;

    // ---- PV from LDS V region (no barrier needed; V staged upfront) ----
    float acc[16];
    #pragma unroll
    for (int e = 0; e < 16; ++e) acc[e] = 0.f;

    #pragma unroll
    for (int o = 0; o <= WMAX; ++o) {
        const float pd = quad_bcast(ew[o >> 2], o & 3);
        const unsigned char* rp = buf + VOFF + (qid + WMAX - o) * RS + s * CS;
        uint2 u0 = *(const uint2*)(rp);
        uint2 u1 = *(const uint2*)(rp + 8);
        uint2 u2 = *(const uint2*)(rp + 16);
        uint2 u3 = *(const uint2*)(rp + 24);
        acc[0]  = fmaf(bf_lo(u0.x), pd, acc[0]);  acc[1]  = fmaf(bf_hi(u0.x), pd, acc[1]);
        acc[2]  = fmaf(bf_lo(u0.y), pd, acc[2]);  acc[3]  = fmaf(bf_hi(u0.y), pd, acc[3]);
        acc[4]  = fmaf(bf_lo(u1.x), pd, acc[4]);  acc[5]  = fmaf(bf_hi(u1.x), pd, acc[5]);
        acc[6]  = fmaf(bf_lo(u1.y), pd, acc[6]);  acc[7]  = fmaf(bf_hi(u1.y), pd, acc[7]);
        acc[8]  = fmaf(bf_lo(u2.x), pd, acc[8]);  acc[9]  = fmaf(bf_hi(u2.x), pd, acc[9]);
        acc[10] = fmaf(bf_lo(u2.y), pd, acc[10]); acc[11] = fmaf(bf_hi(u2.y), pd, acc[11]);
        acc[12] = fmaf(bf_lo(u3.x), pd, acc[12]); acc[13] = fmaf(bf_hi(u3.x), pd, acc[13]);
        acc[14] = fmaf(bf_lo(u3.y), pd, acc[14]); acc[15] = fmaf(bf_hi(u3.y), pd, acc[15]);
    }

    #pragma unroll
    for (int dd = 0; dd < NP2; ++dd) {
        const int d = 64 << dd;
        if (t + QPB - 1 >= d) {                // block-uniform skip
            const float pd = quad_bcast(dd < 4 ? ep0 : ep1, (WMAX + 1 + dd) & 3);
            const int j = max(i - d, 0);
            const float* vr = vb + (size_t)j * E + ce;
            #pragma unroll
            for (int u = 0; u < 4; ++u) {
                float4 f = *(const float4*)(vr + u * 4);
                acc[u*4+0] = fmaf(f.x, pd, acc[u*4+0]);
                acc[u*4+1] = fmaf(f.y, pd, acc[u*4+1]);
                acc[u*4+2] = fmaf(f.z, pd, acc[u*4+2]);
                acc[u*4+3] = fmaf(f.w, pd, acc[u*4+3]);
            }
        }
    }

    // ---- write this lane's 64B chunk (quad writes contiguous 256B) ----
    float* op = out + base + (size_t)i * E + ce;
    #pragma unroll
    for (int u = 0; u < 4; ++u) {
        float4 o4;
        o4.x = acc[u*4+0]; o4.y = acc[u*4+1];
        o4.z = acc[u*4+2]; o4.w = acc[u*4+3];
        *(float4*)(op + u * 4) = o4;
    }
}

extern "C" void kernel_launch(void* const* d_in, const int* in_sizes, int n_in,
                              void* d_out, int out_size, void* d_ws, size_t ws_size,
                              hipStream_t stream) {
    const float* q = (const float*)d_in[0];
    const float* k = (const float*)d_in[1];
    const float* v = (const float*)d_in[2];
    const int* win = (const int*)d_in[3];
    float* out = (float*)d_out;

    const int n_rows = in_sizes[0] / E;        // B*H*L = 131072
    const int blocks = n_rows / QPB;           // 2048
    logsparse_attn<<<blocks, 256, 0, stream>>>(q, k, v, out, win);
}

// Round 15
// 48.639 us; speedup vs baseline: 3.0587x; 1.3315x over previous
//
#include <hip/hip_runtime.h>

// Log-sparse attention, B=4 H=8 L=4096 E=64 fp32, win_len<=32.
// Quad-per-query. Round-15 = Round-14 with the fp16 vector types fixed:
// clang's AMD builtins (cvt_pkrtz, fdot2) use __fp16 ext-vectors; arithmetic
// uses _Float16 ext-vectors; bridge with __builtin_bit_cast.
//  - K/V staged in LDS as FP16; scores via v_dot2_f32_f16 (f32 accum);
//  - PV via v_pk_fma_f16 (fp16 accum, 2 elems/op);
//  - staging pack via v_cvt_pkrtz_f16_f32.
// Live set ~45 floats -> expect VGPR ~85-96, 5-6 waves/SIMD (R9-R13
// plateaued 63-65us latency-bound at 4 waves/SIMD, VALUBusy 31%).

constexpr int L     = 4096;
constexpr int E     = 64;
constexpr int QPB   = 64;            // queries per block (256 thr / 4)
constexpr int WMAX  = 32;
constexpr int WROWS = QPB + WMAX;    // 96 staged rows
constexpr int RS    = 160;           // LDS row stride bytes
constexpr int CS    = 40;            // chunk stride bytes (32 data + 8 pad)
constexpr int VOFF  = WROWS * RS;    // V region offset (15360)
constexpr int TPB   = L / QPB;       // 64 tiles per (b,h)
constexpr int NP2   = 6;             // pow2 dists 64..2048

typedef _Float16 h2  __attribute__((ext_vector_type(2)));   // arithmetic type
typedef __fp16   h2c __attribute__((ext_vector_type(2)));   // builtin interop

__device__ __forceinline__ h2 pkrtz(float a, float b) {
    h2c r = __builtin_amdgcn_cvt_pkrtz(a, b);
    return __builtin_bit_cast(h2, r);
}

#if defined(__has_builtin)
#if __has_builtin(__builtin_amdgcn_fdot2)
#define HAVE_FDOT2 1
#endif
#endif

__device__ __forceinline__ float fdot2h(h2 a, h2 b, float c) {
#ifdef HAVE_FDOT2
    return __builtin_amdgcn_fdot2(__builtin_bit_cast(h2c, a),
                                  __builtin_bit_cast(h2c, b), c, false);
#else
    return fmaf((float)a.x, (float)b.x, fmaf((float)a.y, (float)b.y, c));
#endif
}

__device__ __forceinline__ h2 as_h2(unsigned u) {
    return __builtin_bit_cast(h2, u);
}
__device__ __forceinline__ unsigned as_u32(h2 h) {
    return __builtin_bit_cast(unsigned, h);
}

// ---- DPP quad_perm cross-lane (VALU pipe; 4-lane groups) ----
template<int CTRL>
__device__ __forceinline__ float dppf(float x) {
    return __int_as_float(__builtin_amdgcn_update_dpp(
        0, __float_as_int(x), CTRL, 0xF, 0xF, true));
}
__device__ __forceinline__ float quad_sum(float x) {
    x += dppf<0xB1>(x);   // quad_perm [1,0,3,2]
    x += dppf<0x4E>(x);   // quad_perm [2,3,0,1]
    return x;
}
__device__ __forceinline__ float quad_max(float x) {
    x = fmaxf(x, dppf<0xB1>(x));
    x = fmaxf(x, dppf<0x4E>(x));
    return x;
}
__device__ __forceinline__ float quad_bcast(float x, int r) {
    switch (r & 3) {
    case 0:  return dppf<0x00>(x);
    case 1:  return dppf<0x55>(x);
    case 2:  return dppf<0xAA>(x);
    default: return dppf<0xFF>(x);
    }
}

__global__ __launch_bounds__(256) void logsparse_attn(
    const float* __restrict__ q,
    const float* __restrict__ k,
    const float* __restrict__ v,
    float* __restrict__ out,
    const int* __restrict__ win_ptr)
{
    __shared__ alignas(16) unsigned char buf[2 * WROWS * RS];   // 30720 B

    const int bid = blockIdx.x, nb = gridDim.x;
    int swz = bid;
    if ((nb & 7) == 0) {                       // bijective XCD swizzle
        const int cpx = nb >> 3;
        swz = (bid & 7) * cpx + (bid >> 3);
    }
    const int bh  = swz / TPB;
    const int t   = (swz % TPB) * QPB;
    const int tid = threadIdx.x;
    const int qid = tid >> 2;                  // query within block (0..63)
    const int s   = tid & 3;                   // lane within quad = chunk id
    const int i   = t + qid;                   // this quad's query position
    const int ce  = s * 16;                    // chunk base element
    int win = *win_ptr; win = min(win, WMAX);

    const size_t base = (size_t)bh * (L * E);
    const float* kb = k + base;
    const float* vb = v + base;

    // ---- this lane's q chunk as 8 x h2, scale folded (1/8) ----
    h2 qh[8];
    {
        const float* qp = q + base + (size_t)i * E + ce;
        #pragma unroll
        for (int u = 0; u < 4; ++u) {
            float4 f = *(const float4*)(qp + u * 4);
            qh[u*2+0] = pkrtz(f.x * 0.125f, f.y * 0.125f);
            qh[u*2+1] = pkrtz(f.z * 0.125f, f.w * 0.125f);
        }
    }

    // ---- stage K AND V window rows [t-32, t+64) as fp16, chunked layout ----
    // piece w (4 elems) of row r -> region + r*160 + (w>>2)*40 + (w&3)*8
    #pragma unroll
    for (int it = 0; it < 6; ++it) {
        int idx = tid + it * 256;
        int r = idx >> 4, w = idx & 15;
        int cc = w >> 2, p = w & 3;
        int j = max(t - WMAX + r, 0);
        float4 fk = *(const float4*)(kb + (size_t)j * E + w * 4);
        float4 fv = *(const float4*)(vb + (size_t)j * E + w * 4);
        uint2 pk; pk.x = as_u32(pkrtz(fk.x, fk.y)); pk.y = as_u32(pkrtz(fk.z, fk.w));
        uint2 pv; pv.x = as_u32(pkrtz(fv.x, fv.y)); pv.y = as_u32(pkrtz(fv.z, fv.w));
        *(uint2*)(buf + r * RS + cc * CS + p * 8) = pk;
        *(uint2*)(buf + VOFF + r * RS + cc * CS + p * 8) = pv;
    }
    __syncthreads();                 // the ONLY barrier in the kernel

    // ---- scores, distributed: lane s owns keys a with a%4==s ----
    float ws[9];
    float wp[2];
    #pragma unroll
    for (int kk = 0; kk < 9; ++kk) ws[kk] = -60000.f;
    wp[0] = wp[1] = -60000.f;

    // window offsets 0..32 from LDS K (4x b64 per lane; 8 fdot2 per key)
    #pragma unroll
    for (int o = 0; o <= WMAX; ++o) {
        const unsigned char* rp = buf + (qid + WMAX - o) * RS + s * CS;
        uint2 u0 = *(const uint2*)(rp);
        uint2 u1 = *(const uint2*)(rp + 8);
        uint2 u2 = *(const uint2*)(rp + 16);
        uint2 u3 = *(const uint2*)(rp + 24);
        float a0 = 0.f, a1 = 0.f;
        a0 = fdot2h(as_h2(u0.x), qh[0], a0); a1 = fdot2h(as_h2(u0.y), qh[1], a1);
        a0 = fdot2h(as_h2(u1.x), qh[2], a0); a1 = fdot2h(as_h2(u1.y), qh[3], a1);
        a0 = fdot2h(as_h2(u2.x), qh[4], a0); a1 = fdot2h(as_h2(u2.y), qh[5], a1);
        a0 = fdot2h(as_h2(u3.x), qh[6], a0); a1 = fdot2h(as_h2(u3.y), qh[7], a1);
        float sv = quad_sum(a0 + a1);
        const bool isp2  = (o > 0) && ((o & (o - 1)) == 0);
        const bool valid = ((o <= win) || isp2) && (o <= i);
        sv = valid ? sv : -60000.f;
        if (s == (o & 3)) ws[o >> 2] = sv;
    }

    // pow2 dists 64..2048 (global fp32 -> pkrtz -> fdot2)
    #pragma unroll
    for (int dd = 0; dd < NP2; ++dd) {
        const int d = 64 << dd;
        if (t + QPB - 1 >= d) {                // block-uniform skip
            const int j = max(i - d, 0);
            const float* kr = kb + (size_t)j * E + ce;
            float a0 = 0.f, a1 = 0.f;
            #pragma unroll
            for (int u = 0; u < 4; ++u) {
                float4 f = *(const float4*)(kr + u * 4);
                a0 = fdot2h(pkrtz(f.x, f.y), qh[u*2+0], a0);
                a1 = fdot2h(pkrtz(f.z, f.w), qh[u*2+1], a1);
            }
            float sv = quad_sum(a0 + a1);
            sv = (i >= d) ? sv : -60000.f;
            if (s == ((WMAX + 1 + dd) & 3)) wp[dd < 4 ? 0 : 1] = sv;
        }
    }

    // ---- softmax across the quad's distributed scores ----
    float ml = ws[0];
    #pragma unroll
    for (int kk = 1; kk < 9; ++kk) ml = fmaxf(ml, ws[kk]);
    ml = fmaxf(ml, fmaxf(wp[0], wp[1]));
    const float m = quad_max(ml);

    float ew[9], ep0, ep1, dl = 0.f;
    #pragma unroll
    for (int kk = 0; kk < 9; ++kk) { ew[kk] = __expf(ws[kk] - m); dl += ew[kk]; }
    ep0 = __expf(wp[0] - m); ep1 = __expf(wp[1] - m); dl += ep0 + ep1;
    const float inv = 1.0f / quad_sum(dl);
    #pragma unroll
    for (int kk = 0; kk < 9; ++kk) ew[kk] *= inv;
    ep0 *= inv; ep1 *= inv;

    // ---- PV: packed fp16 accumulate, 8 x h2 (elems 2j, 2j+1) ----
    h2 ah[8];
    #pragma unroll
    for (int j = 0; j < 8; ++j) ah[j] = h2{(_Float16)0.f, (_Float16)0.f};

    #pragma unroll
    for (int o = 0; o <= WMAX; ++o) {
        const float pd = quad_bcast(ew[o >> 2], o & 3);   // 0 if masked
        const h2 pdh = pkrtz(pd, pd);
        const unsigned char* rp = buf + VOFF + (qid + WMAX - o) * RS + s * CS;
        uint2 u0 = *(const uint2*)(rp);
        uint2 u1 = *(const uint2*)(rp + 8);
        uint2 u2 = *(const uint2*)(rp + 16);
        uint2 u3 = *(const uint2*)(rp + 24);
        ah[0] += as_h2(u0.x) * pdh; ah[1] += as_h2(u0.y) * pdh;
        ah[2] += as_h2(u1.x) * pdh; ah[3] += as_h2(u1.y) * pdh;
        ah[4] += as_h2(u2.x) * pdh; ah[5] += as_h2(u2.y) * pdh;
        ah[6] += as_h2(u3.x) * pdh; ah[7] += as_h2(u3.y) * pdh;
    }

    #pragma unroll
    for (int dd = 0; dd < NP2; ++dd) {
        const int d = 64 << dd;
        if (t + QPB - 1 >= d) {                // block-uniform skip
            const float pd = quad_bcast(dd < 4 ? ep0 : ep1, (WMAX + 1 + dd) & 3);
            const h2 pdh = pkrtz(pd, pd);
            const int j = max(i - d, 0);
            const float* vr = vb + (size_t)j * E + ce;
            #pragma unroll
            for (int u = 0; u < 4; ++u) {
                float4 f = *(const float4*)(vr + u * 4);
                ah[u*2+0] += pkrtz(f.x, f.y) * pdh;
                ah[u*2+1] += pkrtz(f.z, f.w) * pdh;
            }
        }
    }

    // ---- write this lane's 64B chunk (quad writes contiguous 256B) ----
    float* op = out + base + (size_t)i * E + ce;
    #pragma unroll
    for (int u = 0; u < 4; ++u) {
        float4 o4;
        o4.x = (float)ah[u*2+0].x; o4.y = (float)ah[u*2+0].y;
        o4.z = (float)ah[u*2+1].x; o4.w = (float)ah[u*2+1].y;
        *(float4*)(op + u * 4) = o4;
    }
}

extern "C" void kernel_launch(void* const* d_in, const int* in_sizes, int n_in,
                              void* d_out, int out_size, void* d_ws, size_t ws_size,
                              hipStream_t stream) {
    const float* q = (const float*)d_in[0];
    const float* k = (const float*)d_in[1];
    const float* v = (const float*)d_in[2];
    const int* win = (const int*)d_in[3];
    float* out = (float*)d_out;

    const int n_rows = in_sizes[0] / E;        // B*H*L = 131072
    const int blocks = n_rows / QPB;           // 2048
    logsparse_attn<<<blocks, 256, 0, stream>>>(q, k, v, out, win);
}

// Round 16
// 43.343 us; speedup vs baseline: 3.4324x; 1.1222x over previous
//
#include <hip/hip_runtime.h>

// Log-sparse attention, B=4 H=8 L=4096 E=64 fp32, win_len<=32.
// Quad-per-query, fp16 LDS + fdot2/pk_fma (R15, 48.6us). Round-16: manual
// software pipelining -- R15's allocator chose VGPR=52, serializing every
// key's ds_read(120cyc)->fdot2 chain (VALUBusy 25%). Spend the idle regs
// (budget ~102 at 5 blocks/CU) on in-flight data:
//  - window score/PV: 4-deep register ring (compute key o, reload slot with
//    key o+4 -> ~3 keys of compute covers LDS latency);
//  - pow2 scores BEFORE the barrier (global K, overlaps staging stores);
//  - pow2 PV: 2-deep ring, first loads issued before the window-PV loop.

constexpr int L     = 4096;
constexpr int E     = 64;
constexpr int QPB   = 64;            // queries per block (256 thr / 4)
constexpr int WMAX  = 32;
constexpr int WROWS = QPB + WMAX;    // 96 staged rows
constexpr int RS    = 160;           // LDS row stride bytes
constexpr int CS    = 40;            // chunk stride bytes (32 data + 8 pad)
constexpr int VOFF  = WROWS * RS;    // V region offset (15360)
constexpr int TPB   = L / QPB;       // 64 tiles per (b,h)
constexpr int NP2   = 6;             // pow2 dists 64..2048

typedef _Float16 h2  __attribute__((ext_vector_type(2)));   // arithmetic type
typedef __fp16   h2c __attribute__((ext_vector_type(2)));   // builtin interop

__device__ __forceinline__ h2 pkrtz(float a, float b) {
    h2c r = __builtin_amdgcn_cvt_pkrtz(a, b);
    return __builtin_bit_cast(h2, r);
}

#if defined(__has_builtin)
#if __has_builtin(__builtin_amdgcn_fdot2)
#define HAVE_FDOT2 1
#endif
#endif

__device__ __forceinline__ float fdot2h(h2 a, h2 b, float c) {
#ifdef HAVE_FDOT2
    return __builtin_amdgcn_fdot2(__builtin_bit_cast(h2c, a),
                                  __builtin_bit_cast(h2c, b), c, false);
#else
    return fmaf((float)a.x, (float)b.x, fmaf((float)a.y, (float)b.y, c));
#endif
}

__device__ __forceinline__ h2 as_h2(unsigned u) {
    return __builtin_bit_cast(h2, u);
}
__device__ __forceinline__ unsigned as_u32(h2 h) {
    return __builtin_bit_cast(unsigned, h);
}

// ---- DPP quad_perm cross-lane (VALU pipe; 4-lane groups) ----
template<int CTRL>
__device__ __forceinline__ float dppf(float x) {
    return __int_as_float(__builtin_amdgcn_update_dpp(
        0, __float_as_int(x), CTRL, 0xF, 0xF, true));
}
__device__ __forceinline__ float quad_sum(float x) {
    x += dppf<0xB1>(x);   // quad_perm [1,0,3,2]
    x += dppf<0x4E>(x);   // quad_perm [2,3,0,1]
    return x;
}
__device__ __forceinline__ float quad_max(float x) {
    x = fmaxf(x, dppf<0xB1>(x));
    x = fmaxf(x, dppf<0x4E>(x));
    return x;
}
__device__ __forceinline__ float quad_bcast(float x, int r) {
    switch (r & 3) {
    case 0:  return dppf<0x00>(x);
    case 1:  return dppf<0x55>(x);
    case 2:  return dppf<0xAA>(x);
    default: return dppf<0xFF>(x);
    }
}

__global__ __launch_bounds__(256) void logsparse_attn(
    const float* __restrict__ q,
    const float* __restrict__ k,
    const float* __restrict__ v,
    float* __restrict__ out,
    const int* __restrict__ win_ptr)
{
    __shared__ alignas(16) unsigned char buf[2 * WROWS * RS];   // 30720 B

    const int bid = blockIdx.x, nb = gridDim.x;
    int swz = bid;
    if ((nb & 7) == 0) {                       // bijective XCD swizzle
        const int cpx = nb >> 3;
        swz = (bid & 7) * cpx + (bid >> 3);
    }
    const int bh  = swz / TPB;
    const int t   = (swz % TPB) * QPB;
    const int tid = threadIdx.x;
    const int qid = tid >> 2;                  // query within block (0..63)
    const int s   = tid & 3;                   // lane within quad = chunk id
    const int i   = t + qid;                   // this quad's query position
    const int ce  = s * 16;                    // chunk base element
    int win = *win_ptr; win = min(win, WMAX);

    const size_t base = (size_t)bh * (L * E);
    const float* kb = k + base;
    const float* vb = v + base;

    // ---- this lane's q chunk as 8 x h2, scale folded (1/8) ----
    h2 qh[8];
    {
        const float* qp = q + base + (size_t)i * E + ce;
        #pragma unroll
        for (int u = 0; u < 4; ++u) {
            float4 f = *(const float4*)(qp + u * 4);
            qh[u*2+0] = pkrtz(f.x * 0.125f, f.y * 0.125f);
            qh[u*2+1] = pkrtz(f.z * 0.125f, f.w * 0.125f);
        }
    }

    // ---- stage K AND V window rows [t-32, t+64) as fp16, chunked layout ----
    #pragma unroll
    for (int it = 0; it < 6; ++it) {
        int idx = tid + it * 256;
        int r = idx >> 4, w = idx & 15;
        int cc = w >> 2, p = w & 3;
        int j = max(t - WMAX + r, 0);
        float4 fk = *(const float4*)(kb + (size_t)j * E + w * 4);
        float4 fv = *(const float4*)(vb + (size_t)j * E + w * 4);
        uint2 pk; pk.x = as_u32(pkrtz(fk.x, fk.y)); pk.y = as_u32(pkrtz(fk.z, fk.w));
        uint2 pv; pv.x = as_u32(pkrtz(fv.x, fv.y)); pv.y = as_u32(pkrtz(fv.z, fv.w));
        *(uint2*)(buf + r * RS + cc * CS + p * 8) = pk;
        *(uint2*)(buf + VOFF + r * RS + cc * CS + p * 8) = pv;
    }

    // ---- pow2 scores BEFORE barrier: global K, overlaps staging stores ----
    float wp[2];
    wp[0] = wp[1] = -60000.f;
    #pragma unroll
    for (int dd = 0; dd < NP2; ++dd) {
        const int d = 64 << dd;
        if (t + QPB - 1 >= d) {                // block-uniform skip
            const int j = max(i - d, 0);
            const float* kr = kb + (size_t)j * E + ce;
            float a0 = 0.f, a1 = 0.f;
            #pragma unroll
            for (int u = 0; u < 4; ++u) {
                float4 f = *(const float4*)(kr + u * 4);
                a0 = fdot2h(pkrtz(f.x, f.y), qh[u*2+0], a0);
                a1 = fdot2h(pkrtz(f.z, f.w), qh[u*2+1], a1);
            }
            float sv = quad_sum(a0 + a1);
            sv = (i >= d) ? sv : -60000.f;
            if (s == ((WMAX + 1 + dd) & 3)) wp[dd < 4 ? 0 : 1] = sv;
        }
    }

    __syncthreads();                 // the ONLY barrier in the kernel

    // ---- window scores: 4-deep LDS register ring ----
    float ws[9];
    #pragma unroll
    for (int kk = 0; kk < 9; ++kk) ws[kk] = -60000.f;

    uint2 pf[4][4];
    #pragma unroll
    for (int o = 0; o < 4; ++o) {
        const unsigned char* rp = buf + (qid + WMAX - o) * RS + s * CS;
        pf[o][0] = *(const uint2*)(rp);
        pf[o][1] = *(const uint2*)(rp + 8);
        pf[o][2] = *(const uint2*)(rp + 16);
        pf[o][3] = *(const uint2*)(rp + 24);
    }
    #pragma unroll
    for (int o = 0; o <= WMAX; ++o) {
        float a0 = 0.f, a1 = 0.f;
        a0 = fdot2h(as_h2(pf[o & 3][0].x), qh[0], a0);
        a1 = fdot2h(as_h2(pf[o & 3][0].y), qh[1], a1);
        a0 = fdot2h(as_h2(pf[o & 3][1].x), qh[2], a0);
        a1 = fdot2h(as_h2(pf[o & 3][1].y), qh[3], a1);
        a0 = fdot2h(as_h2(pf[o & 3][2].x), qh[4], a0);
        a1 = fdot2h(as_h2(pf[o & 3][2].y), qh[5], a1);
        a0 = fdot2h(as_h2(pf[o & 3][3].x), qh[6], a0);
        a1 = fdot2h(as_h2(pf[o & 3][3].y), qh[7], a1);
        float sv = quad_sum(a0 + a1);
        const bool isp2  = (o > 0) && ((o & (o - 1)) == 0);
        const bool valid = ((o <= win) || isp2) && (o <= i);
        sv = valid ? sv : -60000.f;
        if (s == (o & 3)) ws[o >> 2] = sv;
        if (o + 4 <= WMAX) {                   // reload this slot with key o+4
            const unsigned char* rp = buf + (qid + WMAX - (o + 4)) * RS + s * CS;
            pf[o & 3][0] = *(const uint2*)(rp);
            pf[o & 3][1] = *(const uint2*)(rp + 8);
            pf[o & 3][2] = *(const uint2*)(rp + 16);
            pf[o & 3][3] = *(const uint2*)(rp + 24);
        }
    }

    // ---- softmax across the quad's distributed scores ----
    float ml = ws[0];
    #pragma unroll
    for (int kk = 1; kk < 9; ++kk) ml = fmaxf(ml, ws[kk]);
    ml = fmaxf(ml, fmaxf(wp[0], wp[1]));
    const float m = quad_max(ml);

    float ew[9], ep0, ep1, dl = 0.f;
    #pragma unroll
    for (int kk = 0; kk < 9; ++kk) { ew[kk] = __expf(ws[kk] - m); dl += ew[kk]; }
    ep0 = __expf(wp[0] - m); ep1 = __expf(wp[1] - m); dl += ep0 + ep1;
    const float inv = 1.0f / quad_sum(dl);
    #pragma unroll
    for (int kk = 0; kk < 9; ++kk) ew[kk] *= inv;
    ep0 *= inv; ep1 *= inv;

    // ---- pow2 PV prefetch (2-deep ring), issued before window PV ----
    float4 vpf[2][4];
    #pragma unroll
    for (int dd = 0; dd < 2; ++dd) {
        if (t + QPB - 1 >= (64 << dd)) {
            const float* vr = vb + (size_t)max(i - (64 << dd), 0) * E + ce;
            vpf[dd][0] = *(const float4*)(vr);
            vpf[dd][1] = *(const float4*)(vr + 4);
            vpf[dd][2] = *(const float4*)(vr + 8);
            vpf[dd][3] = *(const float4*)(vr + 12);
        }
    }

    // ---- window PV: 4-deep LDS register ring, packed fp16 accumulate ----
    h2 ah[8];
    #pragma unroll
    for (int j = 0; j < 8; ++j) ah[j] = h2{(_Float16)0.f, (_Float16)0.f};

    #pragma unroll
    for (int o = 0; o < 4; ++o) {
        const unsigned char* rp = buf + VOFF + (qid + WMAX - o) * RS + s * CS;
        pf[o][0] = *(const uint2*)(rp);
        pf[o][1] = *(const uint2*)(rp + 8);
        pf[o][2] = *(const uint2*)(rp + 16);
        pf[o][3] = *(const uint2*)(rp + 24);
    }
    #pragma unroll
    for (int o = 0; o <= WMAX; ++o) {
        const float pd = quad_bcast(ew[o >> 2], o & 3);   // 0 if masked
        const h2 pdh = pkrtz(pd, pd);
        ah[0] += as_h2(pf[o & 3][0].x) * pdh; ah[1] += as_h2(pf[o & 3][0].y) * pdh;
        ah[2] += as_h2(pf[o & 3][1].x) * pdh; ah[3] += as_h2(pf[o & 3][1].y) * pdh;
        ah[4] += as_h2(pf[o & 3][2].x) * pdh; ah[5] += as_h2(pf[o & 3][2].y) * pdh;
        ah[6] += as_h2(pf[o & 3][3].x) * pdh; ah[7] += as_h2(pf[o & 3][3].y) * pdh;
        if (o + 4 <= WMAX) {
            const unsigned char* rp = buf + VOFF + (qid + WMAX - (o + 4)) * RS + s * CS;
            pf[o & 3][0] = *(const uint2*)(rp);
            pf[o & 3][1] = *(const uint2*)(rp + 8);
            pf[o & 3][2] = *(const uint2*)(rp + 16);
            pf[o & 3][3] = *(const uint2*)(rp + 24);
        }
    }

    // ---- pow2 PV: consume ring, prefetch dd+2 ----
    #pragma unroll
    for (int dd = 0; dd < NP2; ++dd) {
        const int d = 64 << dd;
        if (t + QPB - 1 >= d) {
            const float pd = quad_bcast(dd < 4 ? ep0 : ep1, (WMAX + 1 + dd) & 3);
            const h2 pdh = pkrtz(pd, pd);
            #pragma unroll
            for (int u = 0; u < 4; ++u) {
                float4 f = vpf[dd & 1][u];
                ah[u*2+0] += pkrtz(f.x, f.y) * pdh;
                ah[u*2+1] += pkrtz(f.z, f.w) * pdh;
            }
        }
        if (dd + 2 < NP2 && t + QPB - 1 >= (64 << (dd + 2))) {
            const float* vr = vb + (size_t)max(i - (64 << (dd + 2)), 0) * E + ce;
            vpf[dd & 1][0] = *(const float4*)(vr);
            vpf[dd & 1][1] = *(const float4*)(vr + 4);
            vpf[dd & 1][2] = *(const float4*)(vr + 8);
            vpf[dd & 1][3] = *(const float4*)(vr + 12);
        }
    }

    // ---- write this lane's 64B chunk (quad writes contiguous 256B) ----
    float* op = out + base + (size_t)i * E + ce;
    #pragma unroll
    for (int u = 0; u < 4; ++u) {
        float4 o4;
        o4.x = (float)ah[u*2+0].x; o4.y = (float)ah[u*2+0].y;
        o4.z = (float)ah[u*2+1].x; o4.w = (float)ah[u*2+1].y;
        *(float4*)(op + u * 4) = o4;
    }
}

extern "C" void kernel_launch(void* const* d_in, const int* in_sizes, int n_in,
                              void* d_out, int out_size, void* d_ws, size_t ws_size,
                              hipStream_t stream) {
    const float* q = (const float*)d_in[0];
    const float* k = (const float*)d_in[1];
    const float* v = (const float*)d_in[2];
    const int* win = (const int*)d_in[3];
    float* out = (float*)d_out;

    const int n_rows = in_sizes[0] / E;        // B*H*L = 131072
    const int blocks = n_rows / QPB;           // 2048
    logsparse_attn<<<blocks, 256, 0, stream>>>(q, k, v, out, win);
}